// Round 13
// baseline (274.723 us; speedup 1.0000x reference)
//
#include <hip/hip_runtime.h>
#include <hip/hip_bf16.h>
#include <stdint.h>

#define NROWS 131072
#define LMD   1024
#define GNND  200
#define HD    128
#define BLOCK 256
#define MTILE 32
#define NBLK  (NROWS/MTILE)    // 4096
#define WCH   16384            // W chunk bytes (128 h x 64 k bf16)

typedef __attribute__((ext_vector_type(4))) float  f32x4;
typedef __attribute__((ext_vector_type(8))) short  bf16x8;

#define GLDS(SRC, DST) __builtin_amdgcn_global_load_lds( \
    (const __attribute__((address_space(1))) unsigned int*)(SRC), \
    (__attribute__((address_space(3))) unsigned int*)(DST), 16, 0, 0)
#define SCHED0  __builtin_amdgcn_sched_barrier(0)
#define BAR     __builtin_amdgcn_s_barrier()
#define VMW(N)  asm volatile("s_waitcnt vmcnt(" #N ")" ::: "memory")
#define LGKM0   asm volatile("s_waitcnt lgkmcnt(0)" ::: "memory")

__device__ __forceinline__ short f2bf(float x) {
    union { __hip_bfloat16 h; short s; } u;
    u.h = __float2bfloat16(x);
    return u.s;
}

__device__ __forceinline__ bf16x8 cvt8(f32x4 a, f32x4 b) {
    bf16x8 r;
    r[0]=f2bf(a[0]); r[1]=f2bf(a[1]); r[2]=f2bf(a[2]); r[3]=f2bf(a[3]);
    r[4]=f2bf(b[0]); r[5]=f2bf(b[1]); r[6]=f2bf(b[2]); r[7]=f2bf(b[3]);
    return r;
}

__device__ __forceinline__ float red16(float v) {
    #pragma unroll
    for (int m=1; m<16; m<<=1) v += __shfl_xor(v, m, 16);
    return v;
}

// ---- prep: K=64 chunk-major, swizzle-baked W panels ----
// W1S[ch][row][e] = bf16(lm_W[kk][row]), kk = ch*64 + (e ^ ((row&7)*8))
__global__ void prep_weights(const float* __restrict__ lm_W,
                             const float* __restrict__ gnn_W,
                             short* __restrict__ W1S, short* __restrict__ W2S)
{
    int idx = blockIdx.x*BLOCK + threadIdx.x;     // 512*256 = 131072 = 16 chunks * 8192 shorts
    int row = (idx >> 6) & 127;
    int e   = idx & 63;
    int kk  = (idx >> 13)*64 + (e ^ ((row & 7)*8));
    W1S[idx] = f2bf(lm_W[(long)kk*HD + row]);
    if (idx < 4*8192) {
        W2S[idx] = (kk < GNND) ? f2bf(gnn_W[(long)kk*HD + row]) : (short)0;
    }
}

__global__ __launch_bounds__(BLOCK) void fused(
    const float* __restrict__ lm,  const float* __restrict__ gnn,
    const float* __restrict__ ngn,
    const float* __restrict__ lm_b, const float* __restrict__ gnn_b,
    const char* __restrict__ W1S,  const char* __restrict__ W2S,
    float* __restrict__ partials)
{
    __shared__ short lbuf[4*8192];      // 64 KB: W bufs b0..b3
    __shared__ float esumP[2][32][3];   // pos epilogue partials [colg][row][lg,ll,gg]
    __shared__ float esumN[2][32][3];   // neg epilogue partials
    __shared__ float sp[4], sn[4];

    const int tid  = threadIdx.x;
    const int lane = tid & 63;
    const int win  = tid >> 6;
    const int col  = lane & 15;
    const int g    = lane >> 4;
    const int rowg = win & 1;           // row-group (0: rows 0-15, 1: rows 16-31)
    const int colg = win >> 1;          // col-group (0: h 0-63, 1: h 64-127)
    const int colbase = colg*64;
    const int wq   = win*4096 + lane*16;           // wave's staging quarter
    const long R0  = (long)blockIdx.x * MTILE;
    const long row = R0 + rowg*16 + col;
    const int rotg = blockIdx.x & 7;               // k-phase rotation

    const char* aL = (const char*)lm  + row*(LMD*4L)  + g*32;
    const char* aG = (const char*)gnn + row*(GNND*4L) + g*32;
    const char* aN = (const char*)ngn + row*(GNND*4L) + g*32;
    const char* clampG = (const char*)gnn + (size_t)NROWS*GNND*4 - 16;
    const char* clampN = (const char*)ngn + (size_t)NROWS*GNND*4 - 16;

    const float CC   = 1.0f / 11008.0f;
    const float LOGC = -9.3063777f;                // log(1/11008)
    const f32x4 fz = {0.f,0.f,0.f,0.f};

    // rotated lm A-group byte offset
    auto LOFF = [&](int p)->int { return ((p + rotg) & 7) * 512; };
    // rotated W source for physical chunk p
    auto WSRC = [&](int p)->const char* {
        if (p < 16) {
            int lc = 2*(((p >> 1) + rotg) & 7) + (p & 1);
            return W1S + (size_t)lc*WCH;
        }
        return W2S + (size_t)(p - 16)*WCH;
    };

    auto ISSUEW = [&](const char* ws, int b) {
        const char* s = ws + wq;
        char* d = (char*)lbuf + (size_t)b*WCH + wq;
        #pragma unroll
        for (int i=0;i<4;i++) GLDS(s + i*1024, d + i*1024);
    };
    auto LOADG = [&](const char* base, int off, const char* cl, f32x4 (&S)[8]) {
        #pragma unroll
        for (int j=0;j<4;j++) {
            const char* p0 = base + off + j*128;
            const char* p1 = p0 + 16;
            if (cl) { if (p0 > cl) p0 = cl;  if (p1 > cl) p1 = cl; }
            S[2*j]   = *(const f32x4*)p0;
            S[2*j+1] = *(const f32x4*)p1;
        }
    };
    // one K=64 chunk: this wave's 16 rows x 64 cols (colbase..colbase+63)
    auto COMP = [&](int c, int half, f32x4 (&S)[8], f32x4 (&acc)[4]) {
        const short* wb = lbuf + (c & 3)*8192 + (colbase + col)*64;
        const int sw = (col & 7)*8;
        #pragma unroll
        for (int ks=0; ks<2; ++ks) {
            bf16x8 af = cvt8(S[half*4 + 2*ks], S[half*4 + 2*ks + 1]);
            const short* cb = wb + ((ks*32 + g*8) ^ sw);
            #pragma unroll
            for (int t=0;t<4;t++) {
                bf16x8 wf = *(const bf16x8*)(cb + t*1024);
                acc[t] = __builtin_amdgcn_mfma_f32_16x16x32_bf16(af, wf, acc[t], 0,0,0);
            }
        }
    };

    f32x4 accL[4], accG[4];
    #pragma unroll
    for (int t=0;t<4;t++) accL[t] = fz;
    f32x4 SA[8], SB[8];
    float pos_acc = 0.f, neg_acc = 0.f;

    // ---- prologue: biases, W0-2, Agrp0-1 ----
    float bl[4], bg[4];
    #pragma unroll
    for (int t=0;t<4;t++) bl[t] = lm_b[colbase + t*16 + col];
    #pragma unroll
    for (int t=0;t<4;t++) bg[t] = gnn_b[colbase + t*16 + col];
    SCHED0;
    ISSUEW(WSRC(0), 0); ISSUEW(WSRC(1), 1); ISSUEW(WSRC(2), 2);
    LOADG(aL, LOFF(0), nullptr, SA);
    LOADG(aL, LOFF(1), nullptr, SB);
    SCHED0; VMW(24); SCHED0; BAR; SCHED0;
    #pragma unroll
    for (int t=0;t<4;t++) { asm volatile("" : "+v"(bl[t])); asm volatile("" : "+v"(bg[t])); }

    // ---- lm phase: groups 0..7 (chunks 0..15) ----
    #pragma unroll
    for (int gg=0; gg<8; ++gg) {
        f32x4 (&S)[8] = (gg & 1) ? SB : SA;
        // even chunk 2gg
        ISSUEW(WSRC(2*gg+3), (2*gg+3) & 3);
        SCHED0;
        COMP(2*gg, 0, S, accL);
        SCHED0; VMW(16); SCHED0; BAR; SCHED0;
        // odd chunk 2gg+1
        ISSUEW(WSRC(2*gg+4), (2*gg+4) & 3);
        SCHED0;
        COMP(2*gg+1, 1, S, accL);
        SCHED0;
        if (gg < 6)       LOADG(aL, LOFF(gg+2), nullptr, S);   // grp gg+2 (lm, rotated)
        else if (gg == 6) LOADG(aG,   0, clampG, S);           // grp 8 (gnn)
        else              LOADG(aG, 512, clampG, S);           // grp 9 (gnn)
        SCHED0; VMW(24); SCHED0; BAR; SCHED0;
    }

    // lm bias epilogue
    #pragma unroll
    for (int t=0;t<4;t++) {
        #pragma unroll
        for (int r=0;r<4;r++) accL[t][r] += bl[t];
    }
    #pragma unroll
    for (int t=0;t<4;t++) accG[t] = fz;

    // ---- pos phase: chunks 16..19 ----
    ISSUEW(WSRC(19), 3);
    SCHED0;
    COMP(16, 0, SA, accG);
    SCHED0; VMW(16); SCHED0; BAR; SCHED0;

    COMP(17, 1, SA, accG);
    SCHED0;
    LOADG(aN, 0, clampN, SA);                                  // grp 10 (ngn)
    SCHED0; VMW(20); SCHED0; BAR; SCHED0;

    COMP(18, 0, SB, accG);
    SCHED0; VMW(8); SCHED0; BAR; SCHED0;

    COMP(19, 1, SB, accG);
    SCHED0;
    LOADG(aN, 512, clampN, SB);                                // grp 11 (ngn)
    SCHED0;
    // no vmem waits from here: W2 resident in b0..b3; ngn A in flight

    // ---- pos epilogue: per-wave 64-col partials -> LDS -> combine ----
    #pragma unroll
    for (int r=0;r<4;r++) {
        float lg=0.f, ll=0.f, gg2=0.f;
        #pragma unroll
        for (int t=0;t<4;t++) {
            float lv=accL[t][r], gv=accG[t][r]+bg[t];
            lg += lv*gv; ll += lv*lv; gg2 += gv*gv;
        }
        lg=red16(lg); ll=red16(ll); gg2=red16(gg2);
        if (col==0) {
            int rr = rowg*16 + g*4 + r;
            esumP[colg][rr][0]=lg; esumP[colg][rr][1]=ll; esumP[colg][rr][2]=gg2;
        }
    }
    SCHED0; LGKM0; SCHED0; BAR; SCHED0;      // LDS-only barrier (vmcnt untouched)
    if (win < 2 && lane < 16) {
        int rr = rowg*16 + lane;
        float lg  = esumP[0][rr][0] + esumP[1][rr][0];
        float ll  = esumP[0][rr][1] + esumP[1][rr][1];
        float gg2 = esumP[0][rr][2] + esumP[1][rr][2];
        float d  = lg * rsqrtf(ll*gg2);
        pos_acc = d - logf(expf(d)+CC);      // log(ratio)
    }
    #pragma unroll
    for (int t=0;t<4;t++) accG[t] = fz;

    // ---- neg phase: chunks 20..23 (barrier-free, desynced) ----
    COMP(20, 0, SA, accG);
    COMP(21, 1, SA, accG);
    COMP(22, 0, SB, accG);
    COMP(23, 1, SB, accG);

    // ---- neg epilogue ----
    #pragma unroll
    for (int r=0;r<4;r++) {
        float ln=0.f, nn=0.f, ll=0.f;
        #pragma unroll
        for (int t=0;t<4;t++) {
            float lv=accL[t][r], nv=accG[t][r]+bg[t];
            ln += lv*nv; nn += nv*nv; ll += lv*lv;
        }
        ln=red16(ln); nn=red16(nn); ll=red16(ll);
        if (col==0) {
            int rr = rowg*16 + g*4 + r;
            esumN[colg][rr][0]=ln; esumN[colg][rr][1]=nn; esumN[colg][rr][2]=ll;
        }
    }
    SCHED0; LGKM0; SCHED0; BAR; SCHED0;
    if (win < 2 && lane < 16) {
        int rr = rowg*16 + lane;
        float ln = esumN[0][rr][0] + esumN[1][rr][0];
        float nn = esumN[0][rr][1] + esumN[1][rr][1];
        float ll = esumN[0][rr][2] + esumN[1][rr][2];
        float d  = ln * rsqrtf(ll*nn);
        neg_acc = LOGC - logf(expf(d)+CC);   // log(1-ratio)
    }

    // ---- wave + block reduce ----
    #pragma unroll
    for (int m=1;m<64;m<<=1) {
        pos_acc += __shfl_xor(pos_acc, m, 64);
        neg_acc += __shfl_xor(neg_acc, m, 64);
    }
    if (lane==0) { sp[win]=pos_acc; sn[win]=neg_acc; }
    __syncthreads();
    if (tid==0) {
        float p=0.f,n=0.f;
        #pragma unroll
        for (int w=0;w<4;w++){ p+=sp[w]; n+=sn[w]; }
        partials[blockIdx.x*2]   = p;
        partials[blockIdx.x*2+1] = n;
    }
}

__global__ void finalize(const float* __restrict__ partials, float* __restrict__ out)
{
    __shared__ float sp[BLOCK], sn[BLOCK];
    float p=0.f, n=0.f;
    for (int i=threadIdx.x; i<NBLK; i+=BLOCK) { p += partials[2*i]; n += partials[2*i+1]; }
    sp[threadIdx.x]=p; sn[threadIdx.x]=n;
    __syncthreads();
    for (int s=BLOCK/2; s>0; s>>=1) {
        if (threadIdx.x < s) { sp[threadIdx.x]+=sp[threadIdx.x+s]; sn[threadIdx.x]+=sn[threadIdx.x+s]; }
        __syncthreads();
    }
    if (threadIdx.x==0) out[0] = -(sp[0]+sn[0]) / (float)NROWS;
}

extern "C" void kernel_launch(void* const* d_in, const int* in_sizes, int n_in,
                              void* d_out, int out_size, void* d_ws, size_t ws_size,
                              hipStream_t stream)
{
    const float* lm    = (const float*)d_in[0];
    const float* gnn   = (const float*)d_in[1];
    const float* ngn   = (const float*)d_in[2];
    const float* lm_W  = (const float*)d_in[3];
    const float* lm_b  = (const float*)d_in[4];
    const float* gnn_W = (const float*)d_in[5];
    const float* gnn_b = (const float*)d_in[6];

    short* W1S = (short*)d_ws;                                   // 16*16384 = 262144 B
    short* W2S = (short*)((char*)d_ws + 262144);                 //  4*16384 =  65536 B
    float* partials = (float*)((char*)d_ws + 262144 + 65536);    // 32 KB

    prep_weights<<<512, BLOCK, 0, stream>>>(lm_W, gnn_W, W1S, W2S);
    fused<<<NBLK, BLOCK, 0, stream>>>(lm, gnn, ngn, lm_b, gnn_b,
                                      (const char*)W1S, (const char*)W2S, partials);
    finalize<<<1, BLOCK, 0, stream>>>(partials, (float*)d_out);
}

// Round 14
// 262.738 us; speedup vs baseline: 1.0456x; 1.0456x over previous
//
#include <hip/hip_runtime.h>
#include <hip/hip_bf16.h>
#include <stdint.h>

#define NROWS 131072
#define LMD   1024
#define GNND  200
#define HD    128
#define BLOCK 256
#define MTILE 64
#define NBLK  (NROWS/MTILE)    // 2048
#define WCH   16384            // W chunk bytes (128 h x 64 k bf16)

typedef __attribute__((ext_vector_type(4))) float  f32x4;
typedef __attribute__((ext_vector_type(8))) short  bf16x8;

#define GLDS(SRC, DST) __builtin_amdgcn_global_load_lds( \
    (const __attribute__((address_space(1))) unsigned int*)(SRC), \
    (__attribute__((address_space(3))) unsigned int*)(DST), 16, 0, 0)
#define SCHED0  __builtin_amdgcn_sched_barrier(0)
#define BAR     __builtin_amdgcn_s_barrier()
#define VMW(N)  asm volatile("s_waitcnt vmcnt(" #N ")" ::: "memory")

__device__ __forceinline__ short f2bf(float x) {
    union { __hip_bfloat16 h; short s; } u;
    u.h = __float2bfloat16(x);
    return u.s;
}

__device__ __forceinline__ bf16x8 cvt8(f32x4 a, f32x4 b) {
    bf16x8 r;
    r[0]=f2bf(a[0]); r[1]=f2bf(a[1]); r[2]=f2bf(a[2]); r[3]=f2bf(a[3]);
    r[4]=f2bf(b[0]); r[5]=f2bf(b[1]); r[6]=f2bf(b[2]); r[7]=f2bf(b[3]);
    return r;
}

__device__ __forceinline__ float red16(float v) {
    #pragma unroll
    for (int m=1; m<16; m<<=1) v += __shfl_xor(v, m, 16);
    return v;
}

// ---- prep: K=64 chunk-major, swizzle-baked W panels ----
// W1S[ch][row][e] = bf16(lm_W[kk][row]), kk = ch*64 + (e ^ ((row&7)*8))
__global__ void prep_weights(const float* __restrict__ lm_W,
                             const float* __restrict__ gnn_W,
                             short* __restrict__ W1S, short* __restrict__ W2S)
{
    int idx = blockIdx.x*BLOCK + threadIdx.x;     // 512*256 = 131072 = 16 chunks * 8192 shorts
    int row = (idx >> 6) & 127;
    int e   = idx & 63;
    int kk  = (idx >> 13)*64 + (e ^ ((row & 7)*8));
    W1S[idx] = f2bf(lm_W[(long)kk*HD + row]);
    if (idx < 4*8192) {
        W2S[idx] = (kk < GNND) ? f2bf(gnn_W[(long)kk*HD + row]) : (short)0;
    }
}

__global__ __launch_bounds__(BLOCK) void fused(
    const float* __restrict__ lm,  const float* __restrict__ gnn,
    const float* __restrict__ ngn,
    const float* __restrict__ lm_b, const float* __restrict__ gnn_b,
    const char* __restrict__ W1S,  const char* __restrict__ W2S,
    float* __restrict__ partials)
{
    __shared__ short lbuf[3*8192];      // 48 KB: W ring b0..b2 -> 3 blocks/CU
    __shared__ float sp[4], sn[4];

    const int tid  = threadIdx.x;
    const int lane = tid & 63;
    const int win  = tid >> 6;
    const int col  = lane & 15;
    const int g    = lane >> 4;
    const int wq   = win*4096 + lane*16;           // wave's staging quarter
    const long row = (long)blockIdx.x * MTILE + win*16 + col;
    const int rotg = blockIdx.x & 7;               // k-phase rotation

    const char* aL = (const char*)lm  + row*(LMD*4L)  + g*32;
    const char* aG = (const char*)gnn + row*(GNND*4L) + g*32;
    const char* aN = (const char*)ngn + row*(GNND*4L) + g*32;
    const char* clampG = (const char*)gnn + (size_t)NROWS*GNND*4 - 16;
    const char* clampN = (const char*)ngn + (size_t)NROWS*GNND*4 - 16;

    const float CC   = 1.0f / 11008.0f;
    const float LOGC = -9.3063777f;                // log(1/11008)
    const f32x4 fz = {0.f,0.f,0.f,0.f};

    // rotated lm A-group byte offset
    auto LOFF = [&](int p)->int { return ((p + rotg) & 7) * 512; };
    // rotated W source for physical chunk p (p>=16: W2 chunks, reused 20-23)
    auto WSRC = [&](int p)->const char* {
        if (p < 16) {
            int lc = 2*(((p >> 1) + rotg) & 7) + (p & 1);
            return W1S + (size_t)lc*WCH;
        }
        return W2S + (size_t)((p - 16) & 3)*WCH;
    };

    auto ISSUEW = [&](const char* ws, int b) {
        const char* s = ws + wq;
        char* d = (char*)lbuf + (size_t)b*WCH + wq;
        #pragma unroll
        for (int i=0;i<4;i++) GLDS(s + i*1024, d + i*1024);
    };
    auto LOADG = [&](const char* base, int off, const char* cl, f32x4 (&S)[8]) {
        #pragma unroll
        for (int j=0;j<4;j++) {
            const char* p0 = base + off + j*128;
            const char* p1 = p0 + 16;
            if (cl) { if (p0 > cl) p0 = cl;  if (p1 > cl) p1 = cl; }
            S[2*j]   = *(const f32x4*)p0;
            S[2*j+1] = *(const f32x4*)p1;
        }
    };
    auto COMP = [&](int c, int half, f32x4 (&S)[8], f32x4 (&acc)[8]) {
        const short* wb = lbuf + (c % 3)*8192 + col*64;
        const int sw = (col & 7)*8;
        #pragma unroll
        for (int ks=0; ks<2; ++ks) {
            bf16x8 af = cvt8(S[half*4 + 2*ks], S[half*4 + 2*ks + 1]);
            const short* cb = wb + ((ks*32 + g*8) ^ sw);
            #pragma unroll
            for (int t=0;t<8;t++) {
                bf16x8 wf = *(const bf16x8*)(cb + t*1024);
                acc[t] = __builtin_amdgcn_mfma_f32_16x16x32_bf16(af, wf, acc[t], 0,0,0);
            }
        }
    };

    f32x4 accL[8], accG[8];
    #pragma unroll
    for (int t=0;t<8;t++) accL[t] = fz;
    f32x4 SA[8], SB[8];
    float pos_acc = 0.f, neg_acc = 0.f;

    // ---- prologue: biases, W0,W1, A0,A1, W2 ----
    float bl[8], bg[8];
    #pragma unroll
    for (int t=0;t<8;t++) bl[t] = lm_b[t*16+col];
    #pragma unroll
    for (int t=0;t<8;t++) bg[t] = gnn_b[t*16+col];
    SCHED0;
    ISSUEW(WSRC(0), 0); ISSUEW(WSRC(1), 1);
    LOADG(aL, LOFF(0), nullptr, SA);
    LOADG(aL, LOFF(1), nullptr, SB);
    ISSUEW(WSRC(2), 2);
    SCHED0; VMW(24); SCHED0; BAR; SCHED0;
    #pragma unroll
    for (int t=0;t<8;t++) { asm volatile("" : "+v"(bl[t])); asm volatile("" : "+v"(bg[t])); }

    // ---- lm phase: groups 0..7 (chunks 0..15), W issued 2-ahead ----
    #pragma unroll
    for (int gg=0; gg<8; ++gg) {
        f32x4 (&S)[8] = (gg & 1) ? SB : SA;
        // even chunk c = 2gg: issue W(c+2)
        if (gg > 0) ISSUEW(WSRC(2*gg+2), (2*gg+2) % 3);
        SCHED0;
        COMP(2*gg, 0, S, accL);
        SCHED0; VMW(12); SCHED0; BAR; SCHED0;
        // odd chunk c = 2gg+1: issue W(c+2), refill A
        ISSUEW(WSRC(2*gg+3), (2*gg+3) % 3);
        SCHED0;
        COMP(2*gg+1, 1, S, accL);
        SCHED0;
        if (gg < 6)       LOADG(aL, LOFF(gg+2), nullptr, S);   // grp gg+2 (lm, rotated)
        else if (gg == 6) LOADG(aG,   0, clampG, S);           // grp 8 (gnn)
        else              LOADG(aG, 512, clampG, S);           // grp 9 (gnn)
        SCHED0; VMW(12); SCHED0; BAR; SCHED0;
    }

    // lm bias epilogue
    #pragma unroll
    for (int t=0;t<8;t++) {
        #pragma unroll
        for (int r=0;r<4;r++) accL[t][r] += bl[t];
    }
    #pragma unroll
    for (int t=0;t<8;t++) accG[t] = fz;

    // ---- pos phase: chunks 16..19 ----
    // c16
    ISSUEW(WSRC(18), 18 % 3);
    SCHED0;
    COMP(16, 0, SA, accG);
    SCHED0; VMW(12); SCHED0; BAR; SCHED0;
    // c17
    ISSUEW(WSRC(19), 19 % 3);
    SCHED0;
    COMP(17, 1, SA, accG);
    SCHED0;
    LOADG(aN, 0, clampN, SA);                                  // grp 10 (ngn)
    SCHED0; VMW(12); SCHED0; BAR; SCHED0;
    // c18
    ISSUEW(WSRC(20), 20 % 3);
    SCHED0;
    COMP(18, 0, SB, accG);
    SCHED0; VMW(12); SCHED0; BAR; SCHED0;
    // c19
    ISSUEW(WSRC(21), 21 % 3);
    SCHED0;
    COMP(19, 1, SB, accG);
    SCHED0;
    LOADG(aN, 512, clampN, SB);                                // grp 11 (ngn)
    SCHED0; VMW(12); SCHED0; BAR; SCHED0;

    // ---- pos epilogue (VALU only; W20/W21 + ngn A in flight underneath) ----
    #pragma unroll
    for (int r=0;r<4;r++) {
        float lg=0.f, ll=0.f, gg2=0.f;
        #pragma unroll
        for (int t=0;t<8;t++) {
            float lv=accL[t][r], gv=accG[t][r]+bg[t];
            lg += lv*gv; ll += lv*lv; gg2 += gv*gv;
        }
        lg=red16(lg); ll=red16(ll); gg2=red16(gg2);
        float d  = lg * rsqrtf(ll*gg2);
        float pi = d - logf(expf(d)+CC);     // log(ratio)
        if (col==0) pos_acc += pi;
    }
    #pragma unroll
    for (int t=0;t<8;t++) accG[t] = fz;

    // ---- neg phase: chunks 20..23 (W2 restaged through the ring) ----
    // c20
    ISSUEW(WSRC(22), 22 % 3);
    SCHED0;
    COMP(20, 0, SA, accG);
    SCHED0; VMW(12); SCHED0; BAR; SCHED0;
    // c21
    ISSUEW(WSRC(23), 23 % 3);
    SCHED0;
    COMP(21, 1, SA, accG);
    SCHED0; VMW(4); SCHED0; BAR; SCHED0;
    // c22
    COMP(22, 0, SB, accG);
    SCHED0; VMW(0); SCHED0; BAR; SCHED0;
    // c23
    COMP(23, 1, SB, accG);

    // ---- neg epilogue ----
    #pragma unroll
    for (int r=0;r<4;r++) {
        float ln=0.f, nn=0.f, ll=0.f;
        #pragma unroll
        for (int t=0;t<8;t++) {
            float lv=accL[t][r], nv=accG[t][r]+bg[t];
            ln += lv*nv; nn += nv*nv; ll += lv*lv;
        }
        ln=red16(ln); nn=red16(nn); ll=red16(ll);
        float d  = ln * rsqrtf(ll*nn);
        float ni = LOGC - logf(expf(d)+CC);  // log(1-ratio)
        if (col==0) neg_acc += ni;
    }

    // ---- wave + block reduce ----
    #pragma unroll
    for (int m=1;m<64;m<<=1) {
        pos_acc += __shfl_xor(pos_acc, m, 64);
        neg_acc += __shfl_xor(neg_acc, m, 64);
    }
    if (lane==0) { sp[win]=pos_acc; sn[win]=neg_acc; }
    __syncthreads();
    if (tid==0) {
        float p=0.f,n=0.f;
        #pragma unroll
        for (int w=0;w<4;w++){ p+=sp[w]; n+=sn[w]; }
        partials[blockIdx.x*2]   = p;
        partials[blockIdx.x*2+1] = n;
    }
}

__global__ void finalize(const float* __restrict__ partials, float* __restrict__ out)
{
    __shared__ float sp[BLOCK], sn[BLOCK];
    float p=0.f, n=0.f;
    for (int i=threadIdx.x; i<NBLK; i+=BLOCK) { p += partials[2*i]; n += partials[2*i+1]; }
    sp[threadIdx.x]=p; sn[threadIdx.x]=n;
    __syncthreads();
    for (int s=BLOCK/2; s>0; s>>=1) {
        if (threadIdx.x < s) { sp[threadIdx.x]+=sp[threadIdx.x+s]; sn[threadIdx.x]+=sn[threadIdx.x+s]; }
        __syncthreads();
    }
    if (threadIdx.x==0) out[0] = -(sp[0]+sn[0]) / (float)NROWS;
}

extern "C" void kernel_launch(void* const* d_in, const int* in_sizes, int n_in,
                              void* d_out, int out_size, void* d_ws, size_t ws_size,
                              hipStream_t stream)
{
    const float* lm    = (const float*)d_in[0];
    const float* gnn   = (const float*)d_in[1];
    const float* ngn   = (const float*)d_in[2];
    const float* lm_W  = (const float*)d_in[3];
    const float* lm_b  = (const float*)d_in[4];
    const float* gnn_W = (const float*)d_in[5];
    const float* gnn_b = (const float*)d_in[6];

    short* W1S = (short*)d_ws;                                   // 16*16384 = 262144 B
    short* W2S = (short*)((char*)d_ws + 262144);                 //  4*16384 =  65536 B
    float* partials = (float*)((char*)d_ws + 262144 + 65536);    // 16 KB

    prep_weights<<<512, BLOCK, 0, stream>>>(lm_W, gnn_W, W1S, W2S);
    fused<<<NBLK, BLOCK, 0, stream>>>(lm, gnn, ngn, lm_b, gnn_b,
                                      (const char*)W1S, (const char*)W2S, partials);
    finalize<<<1, BLOCK, 0, stream>>>(partials, (float*)d_out);
}

// Round 15
// 178.483 us; speedup vs baseline: 1.5392x; 1.4721x over previous
//
#include <hip/hip_runtime.h>
#include <hip/hip_bf16.h>
#include <stdint.h>

#define NROWS 131072
#define LMD   1024
#define GNND  200
#define HD    128
#define BLOCK 256
#define MTILE 64
#define NBLK  (NROWS/MTILE)    // 2048
#define WCH   16384            // W chunk bytes (128 h x 64 k bf16)

typedef __attribute__((ext_vector_type(4))) float  f32x4;
typedef __attribute__((ext_vector_type(8))) short  bf16x8;

#define GLDS(SRC, DST) __builtin_amdgcn_global_load_lds( \
    (const __attribute__((address_space(1))) unsigned int*)(SRC), \
    (__attribute__((address_space(3))) unsigned int*)(DST), 16, 0, 0)
#define SCHED0  __builtin_amdgcn_sched_barrier(0)
#define BAR     __builtin_amdgcn_s_barrier()
#define VMW(N)  asm volatile("s_waitcnt vmcnt(" #N ")" ::: "memory")
#define LGKM0   asm volatile("s_waitcnt lgkmcnt(0)" ::: "memory")

__device__ __forceinline__ short f2bf(float x) {
    union { __hip_bfloat16 h; short s; } u;
    u.h = __float2bfloat16(x);
    return u.s;
}

__device__ __forceinline__ bf16x8 cvt8(f32x4 a, f32x4 b) {
    bf16x8 r;
    r[0]=f2bf(a[0]); r[1]=f2bf(a[1]); r[2]=f2bf(a[2]); r[3]=f2bf(a[3]);
    r[4]=f2bf(b[0]); r[5]=f2bf(b[1]); r[6]=f2bf(b[2]); r[7]=f2bf(b[3]);
    return r;
}

__device__ __forceinline__ float red16(float v) {
    #pragma unroll
    for (int m=1; m<16; m<<=1) v += __shfl_xor(v, m, 16);
    return v;
}

// ---- prep: K=64 chunk-major, swizzle-baked W panels ----
// W1S[ch][row][e] = bf16(lm_W[kk][row]), kk = ch*64 + (e ^ ((row&7)*8))
__global__ void prep_weights(const float* __restrict__ lm_W,
                             const float* __restrict__ gnn_W,
                             short* __restrict__ W1S, short* __restrict__ W2S)
{
    int idx = blockIdx.x*BLOCK + threadIdx.x;     // 512*256 = 131072 = 16 chunks * 8192 shorts
    int row = (idx >> 6) & 127;
    int e   = idx & 63;
    int kk  = (idx >> 13)*64 + (e ^ ((row & 7)*8));
    W1S[idx] = f2bf(lm_W[(long)kk*HD + row]);
    if (idx < 4*8192) {
        W2S[idx] = (kk < GNND) ? f2bf(gnn_W[(long)kk*HD + row]) : (short)0;
    }
}

__global__ __launch_bounds__(BLOCK, 2) void fused(
    const float* __restrict__ lm,  const float* __restrict__ gnn,
    const float* __restrict__ ngn,
    const float* __restrict__ lm_b, const float* __restrict__ gnn_b,
    const char* __restrict__ W1S,  const char* __restrict__ W2S,
    float* __restrict__ partials)
{
    __shared__ short lbuf[4*8192];      // 64 KB: W bufs b0..b3
    __shared__ float biasLDS[256];      // [0:128) lm_b, [128:256) gnn_b
    __shared__ float sp[4], sn[4];

    const int tid  = threadIdx.x;
    const int lane = tid & 63;
    const int win  = tid >> 6;
    const int col  = lane & 15;
    const int g    = lane >> 4;
    const int wq   = win*4096 + lane*16;           // wave's staging quarter
    const long row = (long)blockIdx.x * MTILE + win*16 + col;
    const int rotg = blockIdx.x & 7;               // k-phase rotation

    const char* aL = (const char*)lm  + row*(LMD*4L)  + g*32;
    const char* aG = (const char*)gnn + row*(GNND*4L) + g*32;
    const char* aN = (const char*)ngn + row*(GNND*4L) + g*32;
    const char* clampG = (const char*)gnn + (size_t)NROWS*GNND*4 - 16;
    const char* clampN = (const char*)ngn + (size_t)NROWS*GNND*4 - 16;

    const float CC   = 1.0f / 11008.0f;
    const float LOGC = -9.3063777f;                // log(1/11008)
    const f32x4 fz = {0.f,0.f,0.f,0.f};

    // rotated lm A-group byte offset
    auto LOFF = [&](int p)->int { return ((p + rotg) & 7) * 512; };
    // rotated W source for physical chunk p
    auto WSRC = [&](int p)->const char* {
        if (p < 16) {
            int lc = 2*(((p >> 1) + rotg) & 7) + (p & 1);
            return W1S + (size_t)lc*WCH;
        }
        return W2S + (size_t)(p - 16)*WCH;
    };

    auto ISSUEW = [&](const char* ws, int b) {
        const char* s = ws + wq;
        char* d = (char*)lbuf + (size_t)b*WCH + wq;
        #pragma unroll
        for (int i=0;i<4;i++) GLDS(s + i*1024, d + i*1024);
    };
    auto LOADG = [&](const char* base, int off, const char* cl, f32x4 (&S)[8]) {
        #pragma unroll
        for (int j=0;j<4;j++) {
            const char* p0 = base + off + j*128;
            const char* p1 = p0 + 16;
            if (cl) { if (p0 > cl) p0 = cl;  if (p1 > cl) p1 = cl; }
            S[2*j]   = *(const f32x4*)p0;
            S[2*j+1] = *(const f32x4*)p1;
        }
    };
    auto COMP = [&](int c, int half, f32x4 (&S)[8], f32x4 (&acc)[8]) {
        const short* wb = lbuf + (c & 3)*8192 + col*64;
        const int sw = (col & 7)*8;
        #pragma unroll
        for (int ks=0; ks<2; ++ks) {
            bf16x8 af = cvt8(S[half*4 + 2*ks], S[half*4 + 2*ks + 1]);
            const short* cb = wb + ((ks*32 + g*8) ^ sw);
            #pragma unroll
            for (int t=0;t<8;t++) {
                bf16x8 wf = *(const bf16x8*)(cb + t*1024);
                acc[t] = __builtin_amdgcn_mfma_f32_16x16x32_bf16(af, wf, acc[t], 0,0,0);
            }
        }
    };

    f32x4 accL[8], accG[8];
    #pragma unroll
    for (int t=0;t<8;t++) accL[t] = fz;
    f32x4 SA[8], SB[8];
    float pos_acc = 0.f, neg_acc = 0.f;

    // ---- prologue: biases -> LDS (drained by ds_write dep before pipeline starts) ----
    {
        float bv = (tid < 128) ? lm_b[tid] : gnn_b[tid - 128];
        biasLDS[tid] = bv;
    }
    SCHED0;
    ISSUEW(WSRC(0), 0); ISSUEW(WSRC(1), 1); ISSUEW(WSRC(2), 2);
    LOADG(aL, LOFF(0), nullptr, SA);
    LOADG(aL, LOFF(1), nullptr, SB);
    SCHED0; VMW(24); LGKM0; SCHED0; BAR; SCHED0;

    // ---- lm phase: groups 0..7 (chunks 0..15) ----
    #pragma unroll
    for (int gg=0; gg<8; ++gg) {
        f32x4 (&S)[8] = (gg & 1) ? SB : SA;
        // even chunk 2gg
        ISSUEW(WSRC(2*gg+3), (2*gg+3) & 3);
        SCHED0;
        COMP(2*gg, 0, S, accL);
        SCHED0; VMW(16); SCHED0; BAR; SCHED0;
        // odd chunk 2gg+1
        ISSUEW(WSRC(2*gg+4), (2*gg+4) & 3);
        SCHED0;
        COMP(2*gg+1, 1, S, accL);
        SCHED0;
        if (gg < 6)       LOADG(aL, LOFF(gg+2), nullptr, S);   // grp gg+2 (lm, rotated)
        else if (gg == 6) LOADG(aG,   0, clampG, S);           // grp 8 (gnn)
        else              LOADG(aG, 512, clampG, S);           // grp 9 (gnn)
        SCHED0; VMW(24); SCHED0; BAR; SCHED0;
    }

    // lm bias epilogue (bias from LDS; lgkmcnt path only)
    #pragma unroll
    for (int t=0;t<8;t++) {
        float blv = biasLDS[t*16+col];
        #pragma unroll
        for (int r=0;r<4;r++) accL[t][r] += blv;
    }
    #pragma unroll
    for (int t=0;t<8;t++) accG[t] = fz;

    // ---- pos phase: chunks 16..19 ----
    ISSUEW(WSRC(19), 3);
    SCHED0;
    COMP(16, 0, SA, accG);
    SCHED0; VMW(16); SCHED0; BAR; SCHED0;

    COMP(17, 1, SA, accG);
    SCHED0;
    LOADG(aN, 0, clampN, SA);                                  // grp 10 (ngn)
    SCHED0; VMW(20); SCHED0; BAR; SCHED0;

    COMP(18, 0, SB, accG);
    SCHED0; VMW(8); SCHED0; BAR; SCHED0;

    COMP(19, 1, SB, accG);
    SCHED0;
    LOADG(aN, 512, clampN, SB);                                // grp 11 (ngn)
    SCHED0;
    // barrier-free from here: W2 resident in b0..b3

    // pos epilogue
    #pragma unroll
    for (int r=0;r<4;r++) {
        float lg=0.f, ll=0.f, gg2=0.f;
        #pragma unroll
        for (int t=0;t<8;t++) {
            float lv=accL[t][r], gv=accG[t][r] + biasLDS[128+t*16+col];
            lg += lv*gv; ll += lv*lv; gg2 += gv*gv;
        }
        lg=red16(lg); ll=red16(ll); gg2=red16(gg2);
        float d  = lg * rsqrtf(ll*gg2);
        float pi = d - logf(expf(d)+CC);     // log(ratio)
        if (col==0) pos_acc += pi;
    }
    #pragma unroll
    for (int t=0;t<8;t++) accG[t] = fz;

    // ---- neg phase: chunks 20..23 (barrier-free, desynced) ----
    COMP(20, 0, SA, accG);
    COMP(21, 1, SA, accG);
    COMP(22, 0, SB, accG);
    COMP(23, 1, SB, accG);

    // neg epilogue
    #pragma unroll
    for (int r=0;r<4;r++) {
        float ln=0.f, nn=0.f, ll=0.f;
        #pragma unroll
        for (int t=0;t<8;t++) {
            float lv=accL[t][r], nv=accG[t][r] + biasLDS[128+t*16+col];
            ln += lv*nv; nn += nv*nv; ll += lv*lv;
        }
        ln=red16(ln); nn=red16(nn); ll=red16(ll);
        float d  = ln * rsqrtf(ll*nn);
        float ni = LOGC - logf(expf(d)+CC);  // log(1-ratio)
        if (col==0) neg_acc += ni;
    }

    // ---- wave + block reduce ----
    #pragma unroll
    for (int m=1;m<64;m<<=1) {
        pos_acc += __shfl_xor(pos_acc, m, 64);
        neg_acc += __shfl_xor(neg_acc, m, 64);
    }
    if (lane==0) { sp[win]=pos_acc; sn[win]=neg_acc; }
    __syncthreads();
    if (tid==0) {
        float p=0.f,n=0.f;
        #pragma unroll
        for (int w=0;w<4;w++){ p+=sp[w]; n+=sn[w]; }
        partials[blockIdx.x*2]   = p;
        partials[blockIdx.x*2+1] = n;
    }
}

__global__ void finalize(const float* __restrict__ partials, float* __restrict__ out)
{
    __shared__ float sp[BLOCK], sn[BLOCK];
    float p=0.f, n=0.f;
    for (int i=threadIdx.x; i<NBLK; i+=BLOCK) { p += partials[2*i]; n += partials[2*i+1]; }
    sp[threadIdx.x]=p; sn[threadIdx.x]=n;
    __syncthreads();
    for (int s=BLOCK/2; s>0; s>>=1) {
        if (threadIdx.x < s) { sp[threadIdx.x]+=sp[threadIdx.x+s]; sn[threadIdx.x]+=sn[threadIdx.x+s]; }
        __syncthreads();
    }
    if (threadIdx.x==0) out[0] = -(sp[0]+sn[0]) / (float)NROWS;
}

extern "C" void kernel_launch(void* const* d_in, const int* in_sizes, int n_in,
                              void* d_out, int out_size, void* d_ws, size_t ws_size,
                              hipStream_t stream)
{
    const float* lm    = (const float*)d_in[0];
    const float* gnn   = (const float*)d_in[1];
    const float* ngn   = (const float*)d_in[2];
    const float* lm_W  = (const float*)d_in[3];
    const float* lm_b  = (const float*)d_in[4];
    const float* gnn_W = (const float*)d_in[5];
    const float* gnn_b = (const float*)d_in[6];

    short* W1S = (short*)d_ws;                                   // 16*16384 = 262144 B
    short* W2S = (short*)((char*)d_ws + 262144);                 //  4*16384 =  65536 B
    float* partials = (float*)((char*)d_ws + 262144 + 65536);    // 16 KB

    prep_weights<<<512, BLOCK, 0, stream>>>(lm_W, gnn_W, W1S, W2S);
    fused<<<NBLK, BLOCK, 0, stream>>>(lm, gnn, ngn, lm_b, gnn_b,
                                      (const char*)W1S, (const char*)W2S, partials);
    finalize<<<1, BLOCK, 0, stream>>>(partials, (float*)d_out);
}

// Round 16
// 169.571 us; speedup vs baseline: 1.6201x; 1.0526x over previous
//
#include <hip/hip_runtime.h>
#include <hip/hip_bf16.h>
#include <stdint.h>

#define NROWS 131072
#define LMD   1024
#define GNND  200
#define HD    128
#define BLOCK 512
#define MTILE 128
#define NBLK  (NROWS/MTILE)    // 1024
#define WCH   16384            // W chunk bytes (128 h x 64 k bf16)

typedef __attribute__((ext_vector_type(4))) float  f32x4;
typedef __attribute__((ext_vector_type(8))) short  bf16x8;

#define GLDS(SRC, DST) __builtin_amdgcn_global_load_lds( \
    (const __attribute__((address_space(1))) unsigned int*)(SRC), \
    (__attribute__((address_space(3))) unsigned int*)(DST), 16, 0, 0)
#define SCHED0  __builtin_amdgcn_sched_barrier(0)
#define BAR     __builtin_amdgcn_s_barrier()
#define VMW(N)  asm volatile("s_waitcnt vmcnt(" #N ")" ::: "memory")
#define LGKM0   asm volatile("s_waitcnt lgkmcnt(0)" ::: "memory")

__device__ __forceinline__ short f2bf(float x) {
    union { __hip_bfloat16 h; short s; } u;
    u.h = __float2bfloat16(x);
    return u.s;
}

__device__ __forceinline__ bf16x8 cvt8(f32x4 a, f32x4 b) {
    bf16x8 r;
    r[0]=f2bf(a[0]); r[1]=f2bf(a[1]); r[2]=f2bf(a[2]); r[3]=f2bf(a[3]);
    r[4]=f2bf(b[0]); r[5]=f2bf(b[1]); r[6]=f2bf(b[2]); r[7]=f2bf(b[3]);
    return r;
}

__device__ __forceinline__ float red16(float v) {
    #pragma unroll
    for (int m=1; m<16; m<<=1) v += __shfl_xor(v, m, 16);
    return v;
}

// ---- prep: K=64 chunk-major, swizzle-baked W panels ----
// W1S[ch][row][e] = bf16(lm_W[kk][row]), kk = ch*64 + (e ^ ((row&7)*8))
__global__ void prep_weights(const float* __restrict__ lm_W,
                             const float* __restrict__ gnn_W,
                             short* __restrict__ W1S, short* __restrict__ W2S)
{
    int idx = blockIdx.x*256 + threadIdx.x;       // 512*256 = 131072 = 16 chunks * 8192 shorts
    int row = (idx >> 6) & 127;
    int e   = idx & 63;
    int kk  = (idx >> 13)*64 + (e ^ ((row & 7)*8));
    W1S[idx] = f2bf(lm_W[(long)kk*HD + row]);
    if (idx < 4*8192) {
        W2S[idx] = (kk < GNND) ? f2bf(gnn_W[(long)kk*HD + row]) : (short)0;
    }
}

__global__ __launch_bounds__(BLOCK) void fused(
    const float* __restrict__ lm,  const float* __restrict__ gnn,
    const float* __restrict__ ngn,
    const float* __restrict__ lm_b, const float* __restrict__ gnn_b,
    const char* __restrict__ W1S,  const char* __restrict__ W2S,
    float* __restrict__ partials)
{
    __shared__ short lbuf[4*8192];      // 64 KB: W bufs b0..b3, shared by 8 waves
    __shared__ float biasLDS[256];      // [0:128) lm_b, [128:256) gnn_b
    __shared__ float sp[8], sn[8];

    const int tid  = threadIdx.x;
    const int lane = tid & 63;
    const int win  = tid >> 6;                     // 0..7
    const int col  = lane & 15;
    const int g    = lane >> 4;
    const int wq   = win*2048 + lane*16;           // wave's staging eighth (2KB)
    const long row = (long)blockIdx.x * MTILE + win*16 + col;
    const int rotg = blockIdx.x & 7;               // k-phase rotation

    const char* aL = (const char*)lm  + row*(LMD*4L)  + g*32;
    const char* aG = (const char*)gnn + row*(GNND*4L) + g*32;
    const char* aN = (const char*)ngn + row*(GNND*4L) + g*32;
    const char* clampG = (const char*)gnn + (size_t)NROWS*GNND*4 - 16;
    const char* clampN = (const char*)ngn + (size_t)NROWS*GNND*4 - 16;

    const float CC   = 1.0f / 11008.0f;
    const float LOGC = -9.3063777f;                // log(1/11008)
    const f32x4 fz = {0.f,0.f,0.f,0.f};

    // rotated lm A-group byte offset
    auto LOFF = [&](int p)->int { return ((p + rotg) & 7) * 512; };
    // rotated W source for physical chunk p
    auto WSRC = [&](int p)->const char* {
        if (p < 16) {
            int lc = 2*(((p >> 1) + rotg) & 7) + (p & 1);
            return W1S + (size_t)lc*WCH;
        }
        return W2S + (size_t)(p - 16)*WCH;
    };

    auto ISSUEW = [&](const char* ws, int b) {
        const char* s = ws + wq;
        char* d = (char*)lbuf + (size_t)b*WCH + wq;
        #pragma unroll
        for (int i=0;i<2;i++) GLDS(s + i*1024, d + i*1024);
    };
    auto LOADG = [&](const char* base, int off, const char* cl, f32x4 (&S)[8]) {
        #pragma unroll
        for (int j=0;j<4;j++) {
            const char* p0 = base + off + j*128;
            const char* p1 = p0 + 16;
            if (cl) { if (p0 > cl) p0 = cl;  if (p1 > cl) p1 = cl; }
            S[2*j]   = *(const f32x4*)p0;
            S[2*j+1] = *(const f32x4*)p1;
        }
    };
    auto COMP = [&](int c, int half, f32x4 (&S)[8], f32x4 (&acc)[8]) {
        const short* wb = lbuf + (c & 3)*8192 + col*64;
        const int sw = (col & 7)*8;
        #pragma unroll
        for (int ks=0; ks<2; ++ks) {
            bf16x8 af = cvt8(S[half*4 + 2*ks], S[half*4 + 2*ks + 1]);
            const short* cb = wb + ((ks*32 + g*8) ^ sw);
            #pragma unroll
            for (int t=0;t<8;t++) {
                bf16x8 wf = *(const bf16x8*)(cb + t*1024);
                acc[t] = __builtin_amdgcn_mfma_f32_16x16x32_bf16(af, wf, acc[t], 0,0,0);
            }
        }
    };

    f32x4 accL[8], accG[8];
    #pragma unroll
    for (int t=0;t<8;t++) accL[t] = fz;
    f32x4 SA[8], SB[8];
    float pos_acc = 0.f, neg_acc = 0.f;

    // ---- prologue: biases -> LDS; W0,W1,W2; A(g0),A(g1) ----
    if (tid < 256) {
        float bv = (tid < 128) ? lm_b[tid] : gnn_b[tid - 128];
        biasLDS[tid] = bv;
    }
    SCHED0;
    ISSUEW(WSRC(0), 0); ISSUEW(WSRC(1), 1); ISSUEW(WSRC(2), 2);
    LOADG(aL, LOFF(0), nullptr, SA);
    LOADG(aL, LOFF(1), nullptr, SB);
    SCHED0; VMW(20); LGKM0; SCHED0; BAR; SCHED0;

    // ---- lm phase: groups 0..7 (chunks 0..15) ----
    #pragma unroll
    for (int gg=0; gg<8; ++gg) {
        f32x4 (&S)[8] = (gg & 1) ? SB : SA;
        // even chunk 2gg
        ISSUEW(WSRC(2*gg+3), (2*gg+3) & 3);
        SCHED0;
        COMP(2*gg, 0, S, accL);
        SCHED0; VMW(12); SCHED0; BAR; SCHED0;
        // odd chunk 2gg+1
        ISSUEW(WSRC(2*gg+4), (2*gg+4) & 3);
        SCHED0;
        COMP(2*gg+1, 1, S, accL);
        SCHED0;
        if (gg < 6)       LOADG(aL, LOFF(gg+2), nullptr, S);   // grp gg+2 (lm, rotated)
        else if (gg == 6) LOADG(aG,   0, clampG, S);           // grp 8 (gnn)
        else              LOADG(aG, 512, clampG, S);           // grp 9 (gnn)
        SCHED0; VMW(20); SCHED0; BAR; SCHED0;
    }

    // lm bias epilogue
    #pragma unroll
    for (int t=0;t<8;t++) {
        float blv = biasLDS[t*16+col];
        #pragma unroll
        for (int r=0;r<4;r++) accL[t][r] += blv;
    }
    #pragma unroll
    for (int t=0;t<8;t++) accG[t] = fz;

    // ---- pos phase: chunks 16..19 ----
    ISSUEW(WSRC(19), 3);
    SCHED0;
    COMP(16, 0, SA, accG);
    SCHED0; VMW(12); SCHED0; BAR; SCHED0;

    COMP(17, 1, SA, accG);
    SCHED0;
    LOADG(aN, 0, clampN, SA);                                  // grp 10 (ngn)
    SCHED0; VMW(18); SCHED0; BAR; SCHED0;

    COMP(18, 0, SB, accG);
    SCHED0; VMW(8); SCHED0; BAR; SCHED0;

    COMP(19, 1, SB, accG);
    SCHED0;
    LOADG(aN, 512, clampN, SB);                                // grp 11 (ngn)
    SCHED0;
    // barrier-free from here: W2 resident in b0..b3

    // pos epilogue
    #pragma unroll
    for (int r=0;r<4;r++) {
        float lg=0.f, ll=0.f, gg2=0.f;
        #pragma unroll
        for (int t=0;t<8;t++) {
            float lv=accL[t][r], gv=accG[t][r] + biasLDS[128+t*16+col];
            lg += lv*gv; ll += lv*lv; gg2 += gv*gv;
        }
        lg=red16(lg); ll=red16(ll); gg2=red16(gg2);
        float d  = lg * rsqrtf(ll*gg2);
        float pi = d - logf(expf(d)+CC);     // log(ratio)
        if (col==0) pos_acc += pi;
    }
    #pragma unroll
    for (int t=0;t<8;t++) accG[t] = fz;

    // ---- neg phase: chunks 20..23 (barrier-free, desynced) ----
    COMP(20, 0, SA, accG);
    COMP(21, 1, SA, accG);
    COMP(22, 0, SB, accG);
    COMP(23, 1, SB, accG);

    // neg epilogue
    #pragma unroll
    for (int r=0;r<4;r++) {
        float ln=0.f, nn=0.f, ll=0.f;
        #pragma unroll
        for (int t=0;t<8;t++) {
            float lv=accL[t][r], nv=accG[t][r] + biasLDS[128+t*16+col];
            ln += lv*nv; nn += nv*nv; ll += lv*lv;
        }
        ln=red16(ln); nn=red16(nn); ll=red16(ll);
        float d  = ln * rsqrtf(ll*nn);
        float ni = LOGC - logf(expf(d)+CC);  // log(1-ratio)
        if (col==0) neg_acc += ni;
    }

    // ---- wave + block reduce ----
    #pragma unroll
    for (int m=1;m<64;m<<=1) {
        pos_acc += __shfl_xor(pos_acc, m, 64);
        neg_acc += __shfl_xor(neg_acc, m, 64);
    }
    if (lane==0) { sp[win]=pos_acc; sn[win]=neg_acc; }
    __syncthreads();
    if (tid==0) {
        float p=0.f,n=0.f;
        #pragma unroll
        for (int w=0;w<8;w++){ p+=sp[w]; n+=sn[w]; }
        partials[blockIdx.x*2]   = p;
        partials[blockIdx.x*2+1] = n;
    }
}

__global__ void finalize(const float* __restrict__ partials, float* __restrict__ out)
{
    __shared__ float sp[256], sn[256];
    float p=0.f, n=0.f;
    for (int i=threadIdx.x; i<NBLK; i+=256) { p += partials[2*i]; n += partials[2*i+1]; }
    sp[threadIdx.x]=p; sn[threadIdx.x]=n;
    __syncthreads();
    for (int s=128; s>0; s>>=1) {
        if ((int)threadIdx.x < s) { sp[threadIdx.x]+=sp[threadIdx.x+s]; sn[threadIdx.x]+=sn[threadIdx.x+s]; }
        __syncthreads();
    }
    if (threadIdx.x==0) out[0] = -(sp[0]+sn[0]) / (float)NROWS;
}

extern "C" void kernel_launch(void* const* d_in, const int* in_sizes, int n_in,
                              void* d_out, int out_size, void* d_ws, size_t ws_size,
                              hipStream_t stream)
{
    const float* lm    = (const float*)d_in[0];
    const float* gnn   = (const float*)d_in[1];
    const float* ngn   = (const float*)d_in[2];
    const float* lm_W  = (const float*)d_in[3];
    const float* lm_b  = (const float*)d_in[4];
    const float* gnn_W = (const float*)d_in[5];
    const float* gnn_b = (const float*)d_in[6];

    short* W1S = (short*)d_ws;                                   // 16*16384 = 262144 B
    short* W2S = (short*)((char*)d_ws + 262144);                 //  4*16384 =  65536 B
    float* partials = (float*)((char*)d_ws + 262144 + 65536);    // 8 KB

    prep_weights<<<512, 256, 0, stream>>>(lm_W, gnn_W, W1S, W2S);
    fused<<<NBLK, BLOCK, 0, stream>>>(lm, gnn, ngn, lm_b, gnn_b,
                                      (const char*)W1S, (const char*)W2S, partials);
    finalize<<<1, 256, 0, stream>>>(partials, (float*)d_out);
}

// Round 17
// 163.113 us; speedup vs baseline: 1.6842x; 1.0396x over previous
//
#include <hip/hip_runtime.h>
#include <hip/hip_bf16.h>
#include <stdint.h>

#define NROWS 131072
#define LMD   1024
#define GNND  200
#define HD    128
#define BLOCK 512
#define MTILE 128
#define NBLK  (NROWS/MTILE)    // 1024
#define WCH   16384            // W chunk bytes (128 h x 64 k bf16)

typedef __attribute__((ext_vector_type(4))) float  f32x4;
typedef __attribute__((ext_vector_type(8))) short  bf16x8;

#define GLDS(SRC, DST) __builtin_amdgcn_global_load_lds( \
    (const __attribute__((address_space(1))) unsigned int*)(SRC), \
    (__attribute__((address_space(3))) unsigned int*)(DST), 16, 0, 0)
#define SCHED0  __builtin_amdgcn_sched_barrier(0)
#define BAR     __builtin_amdgcn_s_barrier()
#define VMW(N)  asm volatile("s_waitcnt vmcnt(" #N ")" ::: "memory")
#define LGKM0   asm volatile("s_waitcnt lgkmcnt(0)" ::: "memory")

__device__ __forceinline__ short f2bf(float x) {
    union { __hip_bfloat16 h; short s; } u;
    u.h = __float2bfloat16(x);
    return u.s;
}

__device__ __forceinline__ bf16x8 cvt8(f32x4 a, f32x4 b) {
    bf16x8 r;
    r[0]=f2bf(a[0]); r[1]=f2bf(a[1]); r[2]=f2bf(a[2]); r[3]=f2bf(a[3]);
    r[4]=f2bf(b[0]); r[5]=f2bf(b[1]); r[6]=f2bf(b[2]); r[7]=f2bf(b[3]);
    return r;
}

__device__ __forceinline__ float red16(float v) {
    #pragma unroll
    for (int m=1; m<16; m<<=1) v += __shfl_xor(v, m, 16);
    return v;
}

// ---- prep: K=64 chunk-major, swizzle-baked W panels ----
// W1S[ch][row][e] = bf16(lm_W[kk][row]), kk = ch*64 + (e ^ ((row&7)*8))
__global__ void prep_weights(const float* __restrict__ lm_W,
                             const float* __restrict__ gnn_W,
                             short* __restrict__ W1S, short* __restrict__ W2S)
{
    int idx = blockIdx.x*256 + threadIdx.x;       // 512*256 = 131072 = 16 chunks * 8192 shorts
    int row = (idx >> 6) & 127;
    int e   = idx & 63;
    int kk  = (idx >> 13)*64 + (e ^ ((row & 7)*8));
    W1S[idx] = f2bf(lm_W[(long)kk*HD + row]);
    if (idx < 4*8192) {
        W2S[idx] = (kk < GNND) ? f2bf(gnn_W[(long)kk*HD + row]) : (short)0;
    }
}

__global__ __launch_bounds__(BLOCK) void fused(
    const float* __restrict__ lm,  const float* __restrict__ gnn,
    const float* __restrict__ ngn,
    const float* __restrict__ lm_b, const float* __restrict__ gnn_b,
    const char* __restrict__ W1S,  const char* __restrict__ W2S,
    float* __restrict__ partials)
{
    __shared__ short lbuf[4*8192];      // 64 KB: bufs {0,1}=pair0, {2,3}=pair1
    __shared__ float biasLDS[256];      // [0:128) lm_b, [128:256) gnn_b
    __shared__ float sp[8], sn[8];

    const int tid  = threadIdx.x;
    const int lane = tid & 63;
    const int win  = tid >> 6;                     // 0..7
    const int col  = lane & 15;
    const int g    = lane >> 4;
    const int wq   = win*2048 + lane*16;           // wave's staging eighth (2KB)
    const long row = (long)blockIdx.x * MTILE + win*16 + col;
    const int rotg = blockIdx.x & 7;               // k-phase rotation

    const char* aL = (const char*)lm  + row*(LMD*4L)  + g*32;
    const char* aG = (const char*)gnn + row*(GNND*4L) + g*32;
    const char* aN = (const char*)ngn + row*(GNND*4L) + g*32;
    const char* clampG = (const char*)gnn + (size_t)NROWS*GNND*4 - 16;
    const char* clampN = (const char*)ngn + (size_t)NROWS*GNND*4 - 16;

    const float CC   = 1.0f / 11008.0f;
    const float LOGC = -9.3063777f;                // log(1/11008)
    const f32x4 fz = {0.f,0.f,0.f,0.f};

    // rotated lm A-group byte offset
    auto LOFF = [&](int p)->int { return ((p + rotg) & 7) * 512; };
    // rotated W source for chunk c (c<16: lm, rotated; else W2 chunk c-16)
    auto WSRC = [&](int c)->const char* {
        if (c < 16) {
            int lc = 2*(((c >> 1) + rotg) & 7) + (c & 1);
            return W1S + (size_t)lc*WCH;
        }
        return W2S + (size_t)(c - 16)*WCH;
    };

    auto ISSUEW = [&](const char* ws, int b) {
        const char* s = ws + wq;
        char* d = (char*)lbuf + (size_t)b*WCH + wq;
        #pragma unroll
        for (int i=0;i<2;i++) GLDS(s + i*1024, d + i*1024);
    };
    auto LOADG = [&](const char* base, int off, const char* cl, f32x4 (&S)[8]) {
        #pragma unroll
        for (int j=0;j<4;j++) {
            const char* p0 = base + off + j*128;
            const char* p1 = p0 + 16;
            if (cl) { if (p0 > cl) p0 = cl;  if (p1 > cl) p1 = cl; }
            S[2*j]   = *(const f32x4*)p0;
            S[2*j+1] = *(const f32x4*)p1;
        }
    };
    // one K=64 chunk of MFMA from buf b, A half of S
    auto COMP = [&](int b, int half, f32x4 (&S)[8], f32x4 (&acc)[8]) {
        const short* wb = lbuf + b*8192 + col*64;
        const int sw = (col & 7)*8;
        #pragma unroll
        for (int ks=0; ks<2; ++ks) {
            bf16x8 af = cvt8(S[half*4 + 2*ks], S[half*4 + 2*ks + 1]);
            const short* cb = wb + ((ks*32 + g*8) ^ sw);
            #pragma unroll
            for (int t=0;t<8;t++) {
                bf16x8 wf = *(const bf16x8*)(cb + t*1024);
                acc[t] = __builtin_amdgcn_mfma_f32_16x16x32_bf16(af, wf, acc[t], 0,0,0);
            }
        }
    };

    f32x4 accL[8], accG[8];
    #pragma unroll
    for (int t=0;t<8;t++) accL[t] = fz;
    f32x4 SA[8], SB[8];
    float pos_acc = 0.f, neg_acc = 0.f;

    // ---- prologue: biases -> LDS; Wpair0 (chunks 0,1); A0->SA, A1->SB ----
    if (tid < 256) {
        float bv = (tid < 128) ? lm_b[tid] : gnn_b[tid - 128];
        biasLDS[tid] = bv;
    }
    SCHED0;
    ISSUEW(WSRC(0), 0); ISSUEW(WSRC(1), 1);
    LOADG(aL, LOFF(0), nullptr, SA);
    LOADG(aL, LOFF(1), nullptr, SB);
    SCHED0; VMW(16); LGKM0; SCHED0; BAR; SCHED0;
    // in flight: A0(partially) .. conservative: SA/SB waits are compiler-inserted

    // ---- supersteps 0..7 (lm chunks 0..15): 1 barrier per K=128 ----
    #pragma unroll
    for (int s = 0; s < 8; ++s) {
        f32x4 (&S)[8] = (s & 1) ? SB : SA;
        const int rp = 2*(s & 1);          // read pair base buf
        const int wp = 2*((s+1) & 1);      // write pair base buf (read last SS -> free)
        // stage next W pair (chunks 2s+2, 2s+3; s==7 -> W2 chunks 0,1)
        ISSUEW(WSRC(2*s+2), wp);
        ISSUEW(WSRC(2*s+3), wp+1);
        SCHED0;
        COMP(rp,   0, S, accL);
        COMP(rp+1, 1, S, accL);
        SCHED0;
        if (s < 6)       LOADG(aL, LOFF(s+2), nullptr, S);   // grp s+2 (lm, rotated)
        else if (s == 6) LOADG(aG,   0, clampG, S);          // grp 8 (gnn) -> SA
        else             LOADG(aG, 512, clampG, S);          // grp 9 (gnn) -> SB
        SCHED0; VMW(8); SCHED0; BAR; SCHED0;
    }

    // lm bias epilogue
    #pragma unroll
    for (int t=0;t<8;t++) {
        float blv = biasLDS[t*16+col];
        #pragma unroll
        for (int r=0;r<4;r++) accL[t][r] += blv;
    }
    #pragma unroll
    for (int t=0;t<8;t++) accG[t] = fz;

    // ---- SS8 (pos chunks 16,17; reads pair0 = W2{0,1}) ----
    ISSUEW(WSRC(18), 2);               // W2{2,3} -> pair1
    ISSUEW(WSRC(19), 3);
    SCHED0;
    COMP(0, 0, SA, accG);
    COMP(1, 1, SA, accG);
    SCHED0;
    LOADG(aN, 0, clampN, SA);          // grp 10 (ngn)
    SCHED0; VMW(8); SCHED0; BAR; SCHED0;

    // ---- SS9 (pos chunks 18,19; reads pair1) — last synced superstep ----
    COMP(2, 0, SB, accG);
    COMP(3, 1, SB, accG);
    SCHED0;
    LOADG(aN, 512, clampN, SB);        // grp 11 (ngn)
    SCHED0;
    // barrier-free from here: W2 resident in bufs 0..3, no more LDS writes

    // pos epilogue (ngn loads in flight underneath)
    #pragma unroll
    for (int r=0;r<4;r++) {
        float lg=0.f, ll=0.f, gg2=0.f;
        #pragma unroll
        for (int t=0;t<8;t++) {
            float lv=accL[t][r], gv=accG[t][r] + biasLDS[128+t*16+col];
            lg += lv*gv; ll += lv*lv; gg2 += gv*gv;
        }
        lg=red16(lg); ll=red16(ll); gg2=red16(gg2);
        float d  = lg * rsqrtf(ll*gg2);
        float pi = d - logf(expf(d)+CC);     // log(ratio)
        if (col==0) pos_acc += pi;
    }
    #pragma unroll
    for (int t=0;t<8;t++) accG[t] = fz;

    // ---- SS10, SS11 (neg chunks 20..23; desynced) ----
    COMP(0, 0, SA, accG);
    COMP(1, 1, SA, accG);
    COMP(2, 0, SB, accG);
    COMP(3, 1, SB, accG);

    // neg epilogue
    #pragma unroll
    for (int r=0;r<4;r++) {
        float ln=0.f, nn=0.f, ll=0.f;
        #pragma unroll
        for (int t=0;t<8;t++) {
            float lv=accL[t][r], nv=accG[t][r] + biasLDS[128+t*16+col];
            ln += lv*nv; nn += nv*nv; ll += lv*lv;
        }
        ln=red16(ln); nn=red16(nn); ll=red16(ll);
        float d  = ln * rsqrtf(ll*nn);
        float ni = LOGC - logf(expf(d)+CC);  // log(1-ratio)
        if (col==0) neg_acc += ni;
    }

    // ---- wave + block reduce ----
    #pragma unroll
    for (int m=1;m<64;m<<=1) {
        pos_acc += __shfl_xor(pos_acc, m, 64);
        neg_acc += __shfl_xor(neg_acc, m, 64);
    }
    if (lane==0) { sp[win]=pos_acc; sn[win]=neg_acc; }
    __syncthreads();
    if (tid==0) {
        float p=0.f,n=0.f;
        #pragma unroll
        for (int w=0;w<8;w++){ p+=sp[w]; n+=sn[w]; }
        partials[blockIdx.x*2]   = p;
        partials[blockIdx.x*2+1] = n;
    }
}

__global__ void finalize(const float* __restrict__ partials, float* __restrict__ out)
{
    __shared__ float sp[256], sn[256];
    float p=0.f, n=0.f;
    for (int i=threadIdx.x; i<NBLK; i+=256) { p += partials[2*i]; n += partials[2*i+1]; }
    sp[threadIdx.x]=p; sn[threadIdx.x]=n;
    __syncthreads();
    for (int s=128; s>0; s>>=1) {
        if ((int)threadIdx.x < s) { sp[threadIdx.x]+=sp[threadIdx.x+s]; sn[threadIdx.x]+=sn[threadIdx.x+s]; }
        __syncthreads();
    }
    if (threadIdx.x==0) out[0] = -(sp[0]+sn[0]) / (float)NROWS;
}

extern "C" void kernel_launch(void* const* d_in, const int* in_sizes, int n_in,
                              void* d_out, int out_size, void* d_ws, size_t ws_size,
                              hipStream_t stream)
{
    const float* lm    = (const float*)d_in[0];
    const float* gnn   = (const float*)d_in[1];
    const float* ngn   = (const float*)d_in[2];
    const float* lm_W  = (const float*)d_in[3];
    const float* lm_b  = (const float*)d_in[4];
    const float* gnn_W = (const float*)d_in[5];
    const float* gnn_b = (const float*)d_in[6];

    short* W1S = (short*)d_ws;                                   // 16*16384 = 262144 B
    short* W2S = (short*)((char*)d_ws + 262144);                 //  4*16384 =  65536 B
    float* partials = (float*)((char*)d_ws + 262144 + 65536);    // 8 KB

    prep_weights<<<512, 256, 0, stream>>>(lm_W, gnn_W, W1S, W2S);
    fused<<<NBLK, BLOCK, 0, stream>>>(lm, gnn, ngn, lm_b, gnn_b,
                                      (const char*)W1S, (const char*)W2S, partials);
    finalize<<<1, 256, 0, stream>>>(partials, (float*)d_out);
}

// Round 18
// 161.262 us; speedup vs baseline: 1.7036x; 1.0115x over previous
//
#include <hip/hip_runtime.h>
#include <hip/hip_bf16.h>
#include <stdint.h>

#define NROWS 131072
#define LMD   1024
#define GNND  200
#define HD    128
#define BLOCK 512
#define MTILE 128
#define NBLK  (NROWS/MTILE)    // 1024
#define WCH   16384            // W chunk bytes (128 h x 64 k bf16)
#define DLDS  (8*WCH)          // 128 KB dynamic LDS: 8 W bufs = 4 pairs

typedef __attribute__((ext_vector_type(4))) float  f32x4;
typedef __attribute__((ext_vector_type(8))) short  bf16x8;

#define GLDS(SRC, DST) __builtin_amdgcn_global_load_lds( \
    (const __attribute__((address_space(1))) unsigned int*)(SRC), \
    (__attribute__((address_space(3))) unsigned int*)(DST), 16, 0, 0)
#define SCHED0  __builtin_amdgcn_sched_barrier(0)
#define BAR     __builtin_amdgcn_s_barrier()
#define VMW(N)  asm volatile("s_waitcnt vmcnt(" #N ")" ::: "memory")
#define LGKM0   asm volatile("s_waitcnt lgkmcnt(0)" ::: "memory")

__device__ __forceinline__ short f2bf(float x) {
    union { __hip_bfloat16 h; short s; } u;
    u.h = __float2bfloat16(x);
    return u.s;
}

__device__ __forceinline__ bf16x8 cvt8(f32x4 a, f32x4 b) {
    bf16x8 r;
    r[0]=f2bf(a[0]); r[1]=f2bf(a[1]); r[2]=f2bf(a[2]); r[3]=f2bf(a[3]);
    r[4]=f2bf(b[0]); r[5]=f2bf(b[1]); r[6]=f2bf(b[2]); r[7]=f2bf(b[3]);
    return r;
}

__device__ __forceinline__ float red16(float v) {
    #pragma unroll
    for (int m=1; m<16; m<<=1) v += __shfl_xor(v, m, 16);
    return v;
}

// ---- prep: K=64 chunk-major, swizzle-baked W panels ----
// W1S[ch][row][e] = bf16(lm_W[kk][row]), kk = ch*64 + (e ^ ((row&7)*8))
__global__ void prep_weights(const float* __restrict__ lm_W,
                             const float* __restrict__ gnn_W,
                             short* __restrict__ W1S, short* __restrict__ W2S)
{
    int idx = blockIdx.x*256 + threadIdx.x;       // 512*256 = 131072 = 16 chunks * 8192 shorts
    int row = (idx >> 6) & 127;
    int e   = idx & 63;
    int kk  = (idx >> 13)*64 + (e ^ ((row & 7)*8));
    W1S[idx] = f2bf(lm_W[(long)kk*HD + row]);
    if (idx < 4*8192) {
        W2S[idx] = (kk < GNND) ? f2bf(gnn_W[(long)kk*HD + row]) : (short)0;
    }
}

__global__ __launch_bounds__(BLOCK) void fused(
    const float* __restrict__ lm,  const float* __restrict__ gnn,
    const float* __restrict__ ngn,
    const float* __restrict__ lm_b, const float* __restrict__ gnn_b,
    const char* __restrict__ W1S,  const char* __restrict__ W2S,
    float* __restrict__ partials)
{
    extern __shared__ short lbuf[];     // 128 KB: 8 W bufs; pair p = bufs {2p, 2p+1}
    __shared__ float biasLDS[256];      // [0:128) lm_b, [128:256) gnn_b
    __shared__ float sp[8], sn[8];

    const int tid  = threadIdx.x;
    const int lane = tid & 63;
    const int win  = tid >> 6;                     // 0..7
    const int col  = lane & 15;
    const int g    = lane >> 4;
    const int wq   = win*2048 + lane*16;           // wave's staging eighth (2KB)
    const long row = (long)blockIdx.x * MTILE + win*16 + col;
    const int rotg = blockIdx.x & 7;               // k-phase rotation

    const char* aL = (const char*)lm  + row*(LMD*4L)  + g*32;
    const char* aG = (const char*)gnn + row*(GNND*4L) + g*32;
    const char* aN = (const char*)ngn + row*(GNND*4L) + g*32;
    const char* clampG = (const char*)gnn + (size_t)NROWS*GNND*4 - 16;
    const char* clampN = (const char*)ngn + (size_t)NROWS*GNND*4 - 16;

    const float CC   = 1.0f / 11008.0f;
    const float LOGC = -9.3063777f;                // log(1/11008)
    const f32x4 fz = {0.f,0.f,0.f,0.f};

    // rotated lm A-group byte offset
    auto LOFF = [&](int p)->int { return ((p + rotg) & 7) * 512; };
    // rotated W source for chunk c (c<16: lm, rotated; else W2 chunk c-16)
    auto WSRC = [&](int c)->const char* {
        if (c < 16) {
            int lc = 2*(((c >> 1) + rotg) & 7) + (c & 1);
            return W1S + (size_t)lc*WCH;
        }
        return W2S + (size_t)(c - 16)*WCH;
    };

    auto ISSUEW = [&](const char* ws, int b) {
        const char* s = ws + wq;
        char* d = (char*)lbuf + (size_t)b*WCH + wq;
        #pragma unroll
        for (int i=0;i<2;i++) GLDS(s + i*1024, d + i*1024);
    };
    auto LOADG = [&](const char* base, int off, const char* cl, f32x4 (&S)[8]) {
        #pragma unroll
        for (int j=0;j<4;j++) {
            const char* p0 = base + off + j*128;
            const char* p1 = p0 + 16;
            if (cl) { if (p0 > cl) p0 = cl;  if (p1 > cl) p1 = cl; }
            S[2*j]   = *(const f32x4*)p0;
            S[2*j+1] = *(const f32x4*)p1;
        }
    };
    // one K=64 chunk of MFMA from buf b, A half of S
    auto COMP = [&](int b, int half, f32x4 (&S)[8], f32x4 (&acc)[8]) {
        const short* wb = lbuf + (size_t)b*8192 + col*64;
        const int sw = (col & 7)*8;
        #pragma unroll
        for (int ks=0; ks<2; ++ks) {
            bf16x8 af = cvt8(S[half*4 + 2*ks], S[half*4 + 2*ks + 1]);
            const short* cb = wb + ((ks*32 + g*8) ^ sw);
            #pragma unroll
            for (int t=0;t<8;t++) {
                bf16x8 wf = *(const bf16x8*)(cb + t*1024);
                acc[t] = __builtin_amdgcn_mfma_f32_16x16x32_bf16(af, wf, acc[t], 0,0,0);
            }
        }
    };

    f32x4 accL[8], accG[8];
    #pragma unroll
    for (int t=0;t<8;t++) accL[t] = fz;
    f32x4 SA[8], SB[8];
    float pos_acc = 0.f, neg_acc = 0.f;

    // ---- prologue: biases -> LDS; W pairs 0,1 (chunks 0..3); A0->SA, A1->SB ----
    if (tid < 256) {
        float bv = (tid < 128) ? lm_b[tid] : gnn_b[tid - 128];
        biasLDS[tid] = bv;
    }
    SCHED0;
    ISSUEW(WSRC(0), 0); ISSUEW(WSRC(1), 1);
    ISSUEW(WSRC(2), 2); ISSUEW(WSRC(3), 3);
    LOADG(aL, LOFF(0), nullptr, SA);
    LOADG(aL, LOFF(1), nullptr, SB);
    SCHED0; VMW(16); LGKM0; SCHED0; BAR; SCHED0;   // pairs 0,1 landed; A0,A1 in flight

    // ---- supersteps 0..7 (lm chunks 0..15): barrier every 2 supersteps ----
    #pragma unroll
    for (int s = 0; s < 8; ++s) {
        f32x4 (&S)[8] = (s & 1) ? SB : SA;
        const int rb = (s % 4)*2;            // read pair base buf
        const int wb = ((s+2) % 4)*2;        // write pair base buf (read at s-2)
        // stage pair s+2 (chunks 2s+4, 2s+5; s==6 -> W2{0,1}, s==7 -> W2{2,3})
        ISSUEW(WSRC(2*s+4), wb);
        ISSUEW(WSRC(2*s+5), wb+1);
        SCHED0;
        COMP(rb,   0, S, accL);
        COMP(rb+1, 1, S, accL);
        SCHED0;
        if (s < 6)       LOADG(aL, LOFF(s+2), nullptr, S);   // grp s+2 (lm, rotated)
        else if (s == 6) LOADG(aG,   0, clampG, S);          // grp 8 (gnn) -> SA
        else             LOADG(aG, 512, clampG, S);          // grp 9 (gnn) -> SB
        SCHED0;
        if (s & 1) { VMW(8); SCHED0; BAR; SCHED0; }
    }

    // lm bias epilogue
    #pragma unroll
    for (int t=0;t<8;t++) {
        float blv = biasLDS[t*16+col];
        #pragma unroll
        for (int r=0;r<4;r++) accL[t][r] += blv;
    }
    #pragma unroll
    for (int t=0;t<8;t++) accG[t] = fz;

    // ---- SS8 (pos chunks 16,17; pair0 = W2{0,1}) — barrier-free tail begins ----
    COMP(0, 0, SA, accG);
    COMP(1, 1, SA, accG);
    SCHED0;
    LOADG(aN, 0, clampN, SA);          // grp 10 (ngn)
    SCHED0;

    // ---- SS9 (pos chunks 18,19; pair1 = W2{2,3}) ----
    COMP(2, 0, SB, accG);
    COMP(3, 1, SB, accG);
    SCHED0;
    LOADG(aN, 512, clampN, SB);        // grp 11 (ngn)
    SCHED0;

    // pos epilogue (ngn loads in flight underneath)
    #pragma unroll
    for (int r=0;r<4;r++) {
        float lg=0.f, ll=0.f, gg2=0.f;
        #pragma unroll
        for (int t=0;t<8;t++) {
            float lv=accL[t][r], gv=accG[t][r] + biasLDS[128+t*16+col];
            lg += lv*gv; ll += lv*lv; gg2 += gv*gv;
        }
        lg=red16(lg); ll=red16(ll); gg2=red16(gg2);
        float d  = lg * rsqrtf(ll*gg2);
        float pi = d - logf(expf(d)+CC);     // log(ratio)
        if (col==0) pos_acc += pi;
    }
    #pragma unroll
    for (int t=0;t<8;t++) accG[t] = fz;

    // ---- SS10, SS11 (neg chunks 20..23; W2 resident; desynced) ----
    COMP(0, 0, SA, accG);
    COMP(1, 1, SA, accG);
    COMP(2, 0, SB, accG);
    COMP(3, 1, SB, accG);

    // neg epilogue
    #pragma unroll
    for (int r=0;r<4;r++) {
        float ln=0.f, nn=0.f, ll=0.f;
        #pragma unroll
        for (int t=0;t<8;t++) {
            float lv=accL[t][r], nv=accG[t][r] + biasLDS[128+t*16+col];
            ln += lv*nv; nn += nv*nv; ll += lv*lv;
        }
        ln=red16(ln); nn=red16(nn); ll=red16(ll);
        float d  = ln * rsqrtf(ll*nn);
        float ni = LOGC - logf(expf(d)+CC);  // log(1-ratio)
        if (col==0) neg_acc += ni;
    }

    // ---- wave + block reduce ----
    #pragma unroll
    for (int m=1;m<64;m<<=1) {
        pos_acc += __shfl_xor(pos_acc, m, 64);
        neg_acc += __shfl_xor(neg_acc, m, 64);
    }
    if (lane==0) { sp[win]=pos_acc; sn[win]=neg_acc; }
    __syncthreads();
    if (tid==0) {
        float p=0.f,n=0.f;
        #pragma unroll
        for (int w=0;w<8;w++){ p+=sp[w]; n+=sn[w]; }
        partials[blockIdx.x*2]   = p;
        partials[blockIdx.x*2+1] = n;
    }
}

__global__ void finalize(const float* __restrict__ partials, float* __restrict__ out)
{
    __shared__ float sp[256], sn[256];
    float p=0.f, n=0.f;
    for (int i=threadIdx.x; i<NBLK; i+=256) { p += partials[2*i]; n += partials[2*i+1]; }
    sp[threadIdx.x]=p; sn[threadIdx.x]=n;
    __syncthreads();
    for (int s=128; s>0; s>>=1) {
        if ((int)threadIdx.x < s) { sp[threadIdx.x]+=sp[threadIdx.x+s]; sn[threadIdx.x]+=sn[threadIdx.x+s]; }
        __syncthreads();
    }
    if (threadIdx.x==0) out[0] = -(sp[0]+sn[0]) / (float)NROWS;
}

extern "C" void kernel_launch(void* const* d_in, const int* in_sizes, int n_in,
                              void* d_out, int out_size, void* d_ws, size_t ws_size,
                              hipStream_t stream)
{
    const float* lm    = (const float*)d_in[0];
    const float* gnn   = (const float*)d_in[1];
    const float* ngn   = (const float*)d_in[2];
    const float* lm_W  = (const float*)d_in[3];
    const float* lm_b  = (const float*)d_in[4];
    const float* gnn_W = (const float*)d_in[5];
    const float* gnn_b = (const float*)d_in[6];

    short* W1S = (short*)d_ws;                                   // 16*16384 = 262144 B
    short* W2S = (short*)((char*)d_ws + 262144);                 //  4*16384 =  65536 B
    float* partials = (float*)((char*)d_ws + 262144 + 65536);    // 8 KB

    hipFuncSetAttribute((const void*)fused,
                        hipFuncAttributeMaxDynamicSharedMemorySize, DLDS);

    prep_weights<<<512, 256, 0, stream>>>(lm_W, gnn_W, W1S, W2S);
    fused<<<NBLK, BLOCK, DLDS, stream>>>(lm, gnn, ngn, lm_b, gnn_b,
                                         (const char*)W1S, (const char*)W2S, partials);
    finalize<<<1, 256, 0, stream>>>(partials, (float*)d_out);
}